// Round 6
// baseline (101.535 us; speedup 1.0000x reference)
//
#include <hip/hip_runtime.h>

// CTC forward loss, B=512, T=512 (Tp=510 after [:,2:,:]), C=96, L=64, S=129.
// Round 6: TWO batch elements per wave (A = blockIdx, B = blockIdx + grid).
// With 1 wave/SIMD max, a single DP chain exposes every latency bubble
// (VALU dep latency, DPP hazard wait-states, waitcnt); interleaving two
// independent chains fills them. DP math = round-4/5 validated per-lane
// scaled linear space: lane l holds states 2l,2l+1 (+state 128 on lane 63)
// as mantissas with a per-lane int exponent; zero transcendentals on the
// chain; renorm every 4 steps in steady phase; skip-select folded into FMA.
// log-softmax normalizer: sum_c(p+EPS) == 1 + C*EPS exactly -> constant.

constexpr int   T_    = 512;
constexpr int   C_    = 96;
constexpr int   L_    = 64;
constexpr int   TP_   = 510;          // T - 2
constexpr float EPS_  = 1e-7f;
constexpr float LN2_  = 0.69314718055994530942f;
constexpr float LSE1_ = 1.3849806e-5f;   // log2(1 + C_*EPS_)

typedef float f8 __attribute__((ext_vector_type(8)));

__device__ __forceinline__ float flog2(float x) {
#if __has_builtin(__builtin_amdgcn_logf)
  return __builtin_amdgcn_logf(x);
#else
  return log2f(x);
#endif
}
__device__ __forceinline__ float fexp2(float x) {
#if __has_builtin(__builtin_amdgcn_exp2f)
  return __builtin_amdgcn_exp2f(x);
#else
  return exp2f(x);
#endif
}
__device__ __forceinline__ float fldexp(float x, int n) {
#if __has_builtin(__builtin_amdgcn_ldexpf)
  return __builtin_amdgcn_ldexpf(x, n);
#else
  return __builtin_ldexpf(x, n);
#endif
}

template<int CTRL, int RM, int BM, bool BC>
__device__ __forceinline__ float dppf(float old_, float src) {
  return __int_as_float(__builtin_amdgcn_update_dpp(
      __float_as_int(old_), __float_as_int(src), CTRL, RM, BM, BC));
}
template<int CTRL, int RM, int BM, bool BC>
__device__ __forceinline__ int dppi(int old_, int src) {
  return __builtin_amdgcn_update_dpp(old_, src, CTRL, RM, BM, BC);
}

// log2(2^x + 2^y) — readout only
__device__ __forceinline__ float lae2(float x, float y) {
  float m = fmaxf(x, y);
  return m + flog2(1.f + fexp2(-fabsf(x - y)));
}

// ---- ring load macros: literal element names only (SROA-safe) ----
#define LOADG(PL, PB, CL, CB, T0) {                                  \
  const float* _bl = (CL) + (size_t)(T0) * C_;                       \
  const float* _bb = (CB) + (size_t)(T0) * C_;                       \
  PL.s0=_bl[0*C_]; PB.s0=_bb[0*C_]; PL.s1=_bl[1*C_]; PB.s1=_bb[1*C_];\
  PL.s2=_bl[2*C_]; PB.s2=_bb[2*C_]; PL.s3=_bl[3*C_]; PB.s3=_bb[3*C_];\
  PL.s4=_bl[4*C_]; PB.s4=_bb[4*C_]; PL.s5=_bl[5*C_]; PB.s5=_bb[5*C_];\
  PL.s6=_bl[6*C_]; PB.s6=_bb[6*C_]; PL.s7=_bl[7*C_]; PB.s7=_bb[7*C_]; }

#define LD1C(PL, PB, CL, CB, T0, J) {                                \
  int _t = (T0) + (J); _t = _t < TP_ ? _t : TP_ - 1;                 \
  PL.s##J = (CL)[(size_t)_t * C_]; PB.s##J = (CB)[(size_t)_t * C_]; }
#define LOADGC(PL, PB, CL, CB, T0)                                   \
  LD1C(PL,PB,CL,CB,T0,0) LD1C(PL,PB,CL,CB,T0,1) LD1C(PL,PB,CL,CB,T0,2) \
  LD1C(PL,PB,CL,CB,T0,3) LD1C(PL,PB,CL,CB,T0,4) LD1C(PL,PB,CL,CB,T0,5) \
  LD1C(PL,PB,CL,CB,T0,6) LD1C(PL,PB,CL,CB,T0,7)

#define LOADJ(G, T0)  LOADG(pl##G##A, pb##G##A, colLA, colBA, T0) \
                      LOADG(pl##G##B, pb##G##B, colLB, colBB, T0)
#define LOADJC(G, T0) LOADGC(pl##G##A, pb##G##A, colLA, colBA, T0) \
                      LOADGC(pl##G##B, pb##G##B, colLB, colBB, T0)

// joint (2-problem) step macros
#define JF(G, J) \
  stepF(pl##G##A.s##J, pb##G##A.s##J, mEA, mOA, mXA, eA, skipMA); \
  stepF(pl##G##B.s##J, pb##G##B.s##J, mEB, mOB, mXB, eB, skipMB);
#define A8J(G) { JF(G,0) JF(G,1) JF(G,2) JF(G,3) JF(G,4) JF(G,5) JF(G,6) JF(G,7) }

#define RNS() { renormS(mEA, mOA, mXA, eA, dA); renormS(mEB, mOB, mXB, eB, dB); }
#define JS(G, J) \
  stepS(pl##G##A.s##J, pb##G##A.s##J, mEA, mOA, mXA, dA, skipMA); \
  stepS(pl##G##B.s##J, pb##G##B.s##J, mEB, mOB, mXB, dB, skipMB);
#define B8J(G) { JS(G,0) JS(G,1) JS(G,2) JS(G,3) RNS() JS(G,4) JS(G,5) JS(G,6) JS(G,7) RNS() }

#define TJ(G, J, OFF) \
  if ((tb + (OFF) + (J)) < tmaxA) stepF(pl##G##A.s##J, pb##G##A.s##J, mEA, mOA, mXA, eA, skipMA); \
  if ((tb + (OFF) + (J)) < tmaxB) stepF(pl##G##B.s##J, pb##G##B.s##J, mEB, mOB, mXB, eB, skipMB);
#define T8J(G, OFF) { TJ(G,0,OFF) TJ(G,1,OFF) TJ(G,2,OFF) TJ(G,3,OFF) \
                      TJ(G,4,OFF) TJ(G,5,OFF) TJ(G,6,OFF) TJ(G,7,OFF) }

#define PDECL(P, BEXPR) \
  const int  b##P = (BEXPR); \
  const float* __restrict__ rp##P = y_pred + (size_t)b##P * T_ * C_ + 2 * C_; \
  const int  lab##P = y_true[b##P * L_ + l]; \
  const int  labPrev##P = __shfl_up(lab##P, 1); \
  const float skipM##P = (l >= 1 && lab##P != labPrev##P) ? 1.f : 0.f; \
  const int  ilen##P = input_len[b##P]; \
  const int  llen##P = label_len[b##P]; \
  const int  tmax##P = ilen##P < TP_ ? ilen##P : TP_; \
  const float* __restrict__ colL##P = rp##P + lab##P; \
  const float* __restrict__ colB##P = rp##P + (C_ - 1); \
  float mE##P, mO##P, mX##P = 0.f; int e##P = 0, d##P = 0; \
  mE##P = (l == 0) ? (colB##P[0] + EPS_) : 0.f; \
  mO##P = (l == 0) ? (colL##P[0] + EPS_) : 0.f;

#define READOUT(P) { \
  float ef  = (float)e##P; \
  float lgE = flog2(mE##P) + ef; \
  float lgO = flog2(mO##P) + ef; \
  float aL; \
  if (llen##P >= 64) { float lgX = flog2(mX##P) + ef; aL = __shfl(lgX, 63); } \
  else               { aL = __shfl(lgE, llen##P); } \
  float aP = __shfl(lgO, llen##P - 1); \
  if (l == 0) out[b##P] = -LN2_ * (lae2(aL, aP) - (float)tmax##P * LSE1_); }

__global__ __launch_bounds__(64, 1) void ctc_fwd2(
    const int* __restrict__ y_true, const float* __restrict__ y_pred,
    const int* __restrict__ input_len, const int* __restrict__ label_len,
    float* __restrict__ out)
{
  const int l = threadIdx.x;   // 0..63

  PDECL(A, blockIdx.x)
  PDECL(B, blockIdx.x + gridDim.x)

  f8 pl0A, pl1A, pl2A, pl3A, pb0A, pb1A, pb2A, pb3A;
  f8 pl0B, pl1B, pl2B, pl3B, pb0B, pb1B, pb2B, pb3B;
  LOADJ(0, 1)  LOADJ(1, 9)  LOADJ(2, 17)  LOADJ(3, 25)

  const int tmn = tmaxA < tmaxB ? tmaxA : tmaxB;

  auto runDP = [&](auto hasC) {
    constexpr bool H128 = decltype(hasC)::value;

    // robust step: per-step renorm + empty-lane exponent adoption
    auto stepF = [&](float pl, float pb, float& mE, float& mO, float& mX,
                     int& e, float skipM) {
      float plE = pl + EPS_, pbE = pb + EPS_;
      int   en  = dppi<0x138, 0xf, 0xf, false>(0, e);      // wave_shr1
      float m1  = dppf<0x138, 0xf, 0xf, false>(0.f, mO);
      int   dd  = en - e;  dd = dd < 120 ? dd : 120;
      float a1  = fldexp(m1, dd);                          // finite: dd<=120, m1<2^8
      float nE  = (mE + a1) * pbE;
      float nO  = fmaf(a1, skipM, mO + mE) * plE;
      float nX = 0.f, mx;
      if constexpr (H128) { nX = (mX + mO) * pbE; mx = fmaxf(fmaxf(nE, nO), nX); }
      else                { mx = fmaxf(nE, nO); }
      int  kb = __float_as_int(mx) >> 23;
      int  ks = 127 - kb;
      bool z  = (mx == 0.f);
      e  = z ? en : (e + kb - 127);
      mE = fldexp(nE, ks);
      mO = fldexp(nO, ks);
      if constexpr (H128) mX = fldexp(nX, ks);
    };

    // steady step: no renorm; neighbor shift d frozen since last renormS
    auto stepS = [&](float pl, float pb, float& mE, float& mO, float& mX,
                     int d, float skipM) {
      float plE = pl + EPS_, pbE = pb + EPS_;
      float m1  = dppf<0x138, 0xf, 0xf, false>(0.f, mO);
      float a1  = fldexp(m1, d);
      float nE  = (mE + a1) * pbE;
      float nO  = fmaf(a1, skipM, mO + mE) * plE;
      if constexpr (H128) mX = (mX + mO) * pbE;
      mE = nE; mO = nO;
    };

    auto renormS = [&](float& mE, float& mO, float& mX, int& e, int& d) {
      float mx = fmaxf(mE, mO);
      if constexpr (H128) mx = fmaxf(mx, mX);
      int  kb = __float_as_int(mx) >> 23;
      bool z  = (mx == 0.f);
      int  ks = z ? 0 : (127 - kb);
      e = z ? e : (e + kb - 127);
      mE = fldexp(mE, ks);
      mO = fldexp(mO, ks);
      if constexpr (H128) mX = fldexp(mX, ks);
      int en = dppi<0x138, 0xf, 0xf, false>(0, e);
      int dd = en - e;  d = dd < 120 ? dd : 120;
    };

    int tb = 1;
    // Phase A: robust blocks until all lanes filled (needs t > 64)
#pragma unroll 1
    for (; tb < 65 && tb + 64 <= tmn; tb += 32) {
      A8J(0) LOADJ(0, tb + 32)
      A8J(1) LOADJ(1, tb + 40)
      A8J(2) LOADJ(2, tb + 48)
      A8J(3) LOADJ(3, tb + 56)
    }
    // Phase B: steady (all lanes nonzero: tb >= 65 here whenever it runs)
    RNS()
#pragma unroll 1
    for (; tb + 64 <= tmn; tb += 32) {
      B8J(0) LOADJ(0, tb + 32)
      B8J(1) LOADJ(1, tb + 40)
      B8J(2) LOADJ(2, tb + 48)
      B8J(3) LOADJ(3, tb + 56)
    }
    // Phase C: at most one robust block with clamped refills
#pragma unroll 1
    for (; tb + 32 <= tmn; tb += 32) {
      A8J(0) LOADJC(0, tb + 32)
      A8J(1) LOADJC(1, tb + 40)
      A8J(2) LOADJC(2, tb + 48)
      A8J(3) LOADJC(3, tb + 56)
    }
    // Phase D: guarded ring tail (rings hold t = tb .. tb+31)
    T8J(0, 0) T8J(1, 8) T8J(2, 16) T8J(3, 24)
    // Phase E: slow per-problem tail (never runs when tmaxA == tmaxB)
#pragma unroll 1
    for (int t = tb + 32; t < tmaxA; ++t)
      stepF(colLA[(size_t)t * C_], colBA[(size_t)t * C_], mEA, mOA, mXA, eA, skipMA);
#pragma unroll 1
    for (int t = tb + 32; t < tmaxB; ++t)
      stepF(colLB[(size_t)t * C_], colBB[(size_t)t * C_], mEB, mOB, mXB, eB, skipMB);
  };

  if (llenA >= 64 || llenB >= 64) runDP(std::integral_constant<bool, true>{});
  else                            runDP(std::integral_constant<bool, false>{});

  READOUT(A)
  READOUT(B)
}

extern "C" void kernel_launch(void* const* d_in, const int* in_sizes, int n_in,
                              void* d_out, int out_size, void* d_ws, size_t ws_size,
                              hipStream_t stream) {
  const int*   y_true = (const int*)d_in[0];
  const float* y_pred = (const float*)d_in[1];
  const int*   ilen   = (const int*)d_in[2];
  const int*   llen   = (const int*)d_in[3];
  float*       outp   = (float*)d_out;
  const int    B      = out_size;   // 512 (even)
  hipLaunchKernelGGL(ctc_fwd2, dim3(B / 2), dim3(64), 0, stream,
                     y_true, y_pred, ilen, llen, outp);
}

// Round 7
// 39.774 us; speedup vs baseline: 2.5528x; 2.5528x over previous
//
#include <hip/hip_runtime.h>

// CTC forward loss, B=512, T=512 (Tp=510 after [:,2:,:]), C=96, L=64, S=129.
// One wave per batch element (round-5 structure, 35us validated) with the
// global-gather load path replaced by a coalesced global_load_lds pipeline:
//   - 6-slot LDS ring (6 groups x 8 rows x 96 floats = 18 KB)
//   - stage one row (384 B) with ONE global_load_lds width=16 (lanes 0..23)
//   - counted s_waitcnt vmcnt(24) (never 0), no barriers (single wave)
//   - per-step operands ds_read into named f8 rings one group ahead
// DP math verbatim from rounds 5/6 (absmax 0.0): per-lane scaled linear
// space, mantissas mE,mO(,mX) + per-lane int exponent e; DPP wave_shr1
// neighbor; fill phase per-step renorm + empty-lane adoption; steady phase
// renorm every 4 steps; zero transcendentals on the chain.
// log-softmax normalizer: sum_c(p+EPS) == 1 + C*EPS exactly -> constant.

constexpr int   T_    = 512;
constexpr int   C_    = 96;
constexpr int   L_    = 64;
constexpr int   TP_   = 510;          // T - 2
constexpr float EPS_  = 1e-7f;
constexpr float LN2_  = 0.69314718055994530942f;
constexpr float LSE1_ = 1.3849806e-5f;   // log2(1 + C_*EPS_)

typedef float f8 __attribute__((ext_vector_type(8)));

__device__ __forceinline__ float flog2(float x) {
#if __has_builtin(__builtin_amdgcn_logf)
  return __builtin_amdgcn_logf(x);
#else
  return log2f(x);
#endif
}
__device__ __forceinline__ float fexp2(float x) {
#if __has_builtin(__builtin_amdgcn_exp2f)
  return __builtin_amdgcn_exp2f(x);
#else
  return exp2f(x);
#endif
}
__device__ __forceinline__ float fldexp(float x, int n) {
#if __has_builtin(__builtin_amdgcn_ldexpf)
  return __builtin_amdgcn_ldexpf(x, n);
#else
  return __builtin_ldexpf(x, n);
#endif
}

template<int CTRL, int RM, int BM, bool BC>
__device__ __forceinline__ float dppf(float old_, float src) {
  return __int_as_float(__builtin_amdgcn_update_dpp(
      __float_as_int(old_), __float_as_int(src), CTRL, RM, BM, BC));
}
template<int CTRL, int RM, int BM, bool BC>
__device__ __forceinline__ int dppi(int old_, int src) {
  return __builtin_amdgcn_update_dpp(old_, src, CTRL, RM, BM, BC);
}

// log2(2^x + 2^y) — readout only
__device__ __forceinline__ float lae2(float x, float y) {
  float m = fmaxf(x, y);
  return m + flog2(1.f + fexp2(-fabsf(x - y)));
}

// async global->LDS, 16 B per active lane, LDS dest = uniform base + lane*16
__device__ __forceinline__ void gload_lds16(const float* g, float* lds_) {
  __builtin_amdgcn_global_load_lds(
      (const __attribute__((address_space(1))) void*)g,
      (__attribute__((address_space(3))) void*)lds_,
      16, 0, 0);
}

#define WAITV(N) asm volatile("s_waitcnt vmcnt(" #N ")" ::: "memory")

// ds-read one staged group (8 rows) into a named f8 ring (literal fields)
#define DSRING(SLOT, PL, PB) {                                   \
  const float* _pl = smem + (SLOT) * 768 + lab;                  \
  const float* _pb = smem + (SLOT) * 768 + 95;                   \
  PL.s0 = _pl[0];   PB.s0 = _pb[0];                              \
  PL.s1 = _pl[96];  PB.s1 = _pb[96];                             \
  PL.s2 = _pl[192]; PB.s2 = _pb[192];                            \
  PL.s3 = _pl[288]; PB.s3 = _pb[288];                            \
  PL.s4 = _pl[384]; PB.s4 = _pb[384];                            \
  PL.s5 = _pl[480]; PB.s5 = _pb[480];                            \
  PL.s6 = _pl[576]; PB.s6 = _pb[576];                            \
  PL.s7 = _pl[672]; PB.s7 = _pb[672]; }

#define STEADY8(PL, PB) { renormS();                             \
  stepS(PL.s0,PB.s0); stepS(PL.s1,PB.s1);                        \
  stepS(PL.s2,PB.s2); stepS(PL.s3,PB.s3); renormS();             \
  stepS(PL.s4,PB.s4); stepS(PL.s5,PB.s5);                        \
  stepS(PL.s6,PB.s6); stepS(PL.s7,PB.s7); }

#define GUARD8(T0, PL, PB) {                                     \
  if ((T0)+0 < tmax) stepF(PL.s0,PB.s0);                         \
  if ((T0)+1 < tmax) stepF(PL.s1,PB.s1);                         \
  if ((T0)+2 < tmax) stepF(PL.s2,PB.s2);                         \
  if ((T0)+3 < tmax) stepF(PL.s3,PB.s3);                         \
  if ((T0)+4 < tmax) stepF(PL.s4,PB.s4);                         \
  if ((T0)+5 < tmax) stepF(PL.s5,PB.s5);                         \
  if ((T0)+6 < tmax) stepF(PL.s6,PB.s6);                         \
  if ((T0)+7 < tmax) stepF(PL.s7,PB.s7); }

#define COMPUTEG(K, PL, PB) { const int _t0 = 1 + 8*(K);         \
  if ((K) >= 8 && (_t0 + 7) < tmax) { STEADY8(PL, PB) }          \
  else                              { GUARD8(_t0, PL, PB) } }

__global__ __launch_bounds__(64, 1) void ctc_fwd(
    const int* __restrict__ y_true, const float* __restrict__ y_pred,
    const int* __restrict__ input_len, const int* __restrict__ label_len,
    float* __restrict__ out)
{
  __shared__ float smem[6 * 768];   // 6 slots x 8 rows x 96 floats = 18 KB
  const int b = blockIdx.x;
  const int l = threadIdx.x;   // 0..63

  const float* __restrict__ rp = y_pred + (size_t)b * T_ * C_ + 2 * C_;
  const int  lab     = y_true[b * L_ + l];        // label of odd state 2l+1
  const int  labPrev = __shfl_up(lab, 1);
  const float skipM  = (l >= 1 && lab != labPrev) ? 1.f : 0.f;
  const int  ilen    = input_len[b];
  const int  llen    = label_len[b];               // in [16, 64]
  const int  tmax    = ilen < TP_ ? ilen : TP_;    // 510 for this data

  // stage group g (rows t = 1+8g .. 8+8g, clamped) into LDS slot
  auto stage = [&](int g, int slot) {
    const int t0 = 1 + g * 8;
    float* dst = smem + slot * 768;
    if (l < 24) {
      const float* s0 = rp + 4 * l;
      int t;
      t = t0 + 0; t = t < TP_ ? t : TP_ - 1; gload_lds16(s0 + (size_t)t * C_, dst + 0 * 96);
      t = t0 + 1; t = t < TP_ ? t : TP_ - 1; gload_lds16(s0 + (size_t)t * C_, dst + 1 * 96);
      t = t0 + 2; t = t < TP_ ? t : TP_ - 1; gload_lds16(s0 + (size_t)t * C_, dst + 2 * 96);
      t = t0 + 3; t = t < TP_ ? t : TP_ - 1; gload_lds16(s0 + (size_t)t * C_, dst + 3 * 96);
      t = t0 + 4; t = t < TP_ ? t : TP_ - 1; gload_lds16(s0 + (size_t)t * C_, dst + 4 * 96);
      t = t0 + 5; t = t < TP_ ? t : TP_ - 1; gload_lds16(s0 + (size_t)t * C_, dst + 5 * 96);
      t = t0 + 6; t = t < TP_ ? t : TP_ - 1; gload_lds16(s0 + (size_t)t * C_, dst + 6 * 96);
      t = t0 + 7; t = t < TP_ ? t : TP_ - 1; gload_lds16(s0 + (size_t)t * C_, dst + 7 * 96);
    }
  };

  // per-lane scaled-linear state: alpha = m * 2^e
  float mE, mO, mX = 0.f;
  int   e = 0, d = 0;
  mE = (l == 0) ? (rp[C_ - 1] + EPS_) : 0.f;
  mO = (l == 0) ? (rp[lab] + EPS_) : 0.f;

  auto runDP = [&](auto hasC) {
    constexpr bool H128 = decltype(hasC)::value;

    // robust step: per-step renorm + empty-lane exponent adoption
    auto stepF = [&](float pl, float pb) {
      float plE = pl + EPS_, pbE = pb + EPS_;
      int   en  = dppi<0x138, 0xf, 0xf, false>(0, e);      // wave_shr1
      float m1  = dppf<0x138, 0xf, 0xf, false>(0.f, mO);
      int   dd  = en - e;  dd = dd < 120 ? dd : 120;
      float a1  = fldexp(m1, dd);
      float nE  = (mE + a1) * pbE;
      float nO  = fmaf(a1, skipM, mO + mE) * plE;
      float nX = 0.f, mx;
      if constexpr (H128) { nX = (mX + mO) * pbE; mx = fmaxf(fmaxf(nE, nO), nX); }
      else                { mx = fmaxf(nE, nO); }
      int  kb = __float_as_int(mx) >> 23;
      int  ks = 127 - kb;
      bool z  = (mx == 0.f);
      e  = z ? en : (e + kb - 127);
      mE = fldexp(nE, ks);
      mO = fldexp(nO, ks);
      if constexpr (H128) mX = fldexp(nX, ks);
    };

    // steady step: no renorm; neighbor shift d frozen since last renormS
    auto stepS = [&](float pl, float pb) {
      float plE = pl + EPS_, pbE = pb + EPS_;
      float m1  = dppf<0x138, 0xf, 0xf, false>(0.f, mO);
      float a1  = fldexp(m1, d);
      float nE  = (mE + a1) * pbE;
      float nO  = fmaf(a1, skipM, mO + mE) * plE;
      if constexpr (H128) mX = (mX + mO) * pbE;
      mE = nE; mO = nO;
    };

    auto renormS = [&]() {
      float mx = fmaxf(mE, mO);
      if constexpr (H128) mx = fmaxf(mx, mX);
      int  kb = __float_as_int(mx) >> 23;
      bool z  = (mx == 0.f);
      int  ks = z ? 0 : (127 - kb);
      e = z ? e : (e + kb - 127);
      mE = fldexp(mE, ks);
      mO = fldexp(mO, ks);
      if constexpr (H128) mX = fldexp(mX, ks);
      int en = dppi<0x138, 0xf, 0xf, false>(0, e);
      int dd = en - e;  d = dd < 120 ? dd : 120;
    };

    // ---- pipeline: 64 groups cover t = 1..512 (guards cut at tmax) ----
    stage(0, 0); stage(1, 1); stage(2, 2); stage(3, 3); stage(4, 4);
    WAITV(32);                      // G0 landed
    f8 plA, pbA, plB, pbB;
    DSRING(0, plA, pbA);

    int sR = 1, sS = 5, gS = 5;
#pragma unroll 1
    for (int k = 0; k < 64; k += 2) {
      WAITV(24);                    // G[k+1] landed
      DSRING(sR, plB, pbB); sR = (sR == 5) ? 0 : sR + 1;
      COMPUTEG(k, plA, pbA);
      stage(gS <= 63 ? gS : 63, sS); sS = (sS == 5) ? 0 : sS + 1; ++gS;

      WAITV(24);                    // G[k+2] landed
      DSRING(sR, plA, pbA); sR = (sR == 5) ? 0 : sR + 1;
      COMPUTEG(k + 1, plB, pbB);
      stage(gS <= 63 ? gS : 63, sS); sS = (sS == 5) ? 0 : sS + 1; ++gS;
    }
  };

  if (llen >= 64) runDP(std::integral_constant<bool, true>{});
  else            runDP(std::integral_constant<bool, false>{});

  // readout: log2(alpha) = log2(m) + e   (transcendentals only here)
  float ef  = (float)e;
  float lgE = flog2(mE) + ef;
  float lgO = flog2(mO) + ef;
  float aL;
  if (llen >= 64) { float lgX = flog2(mX) + ef; aL = __shfl(lgX, 63); }
  else            { aL = __shfl(lgE, llen); }
  float aP = __shfl(lgO, llen - 1);
  if (l == 0)
    out[b] = -LN2_ * (lae2(aL, aP) - (float)tmax * LSE1_);
}

extern "C" void kernel_launch(void* const* d_in, const int* in_sizes, int n_in,
                              void* d_out, int out_size, void* d_ws, size_t ws_size,
                              hipStream_t stream) {
  const int*   y_true = (const int*)d_in[0];
  const float* y_pred = (const float*)d_in[1];
  const int*   ilen   = (const int*)d_in[2];
  const int*   llen   = (const int*)d_in[3];
  float*       outp   = (float*)d_out;
  const int    B      = out_size;   // 512
  hipLaunchKernelGGL(ctc_fwd, dim3(B), dim3(64), 0, stream,
                     y_true, y_pred, ilen, llen, outp);
}

// Round 8
// 31.880 us; speedup vs baseline: 3.1849x; 1.2476x over previous
//
#include <hip/hip_runtime.h>

// CTC forward loss, B=512, T=512 (Tp=510 after [:,2:,:]), C=96, L=64, S=129.
// Round 8 = round-5 validated structure (one wave/problem, global gathers,
// named f8 prefetch rings 32 deep, per-lane scaled linear space, absmax 0.0)
// + packed-FP32 steady step: state pair m=(mE,mO) as float2 so the update
//   m = (m + (a1,t)) * (pbE,plE) lowers to v_pk_add_f32 + v_pk_mul_f32.
// DP: lane l holds states 2l,2l+1 (lane 63 also state 128 when llen==64) as
// mantissas with per-lane int exponent e (alpha = m * 2^e). DPP wave_shr1
// neighbor; fill phase (t<=64) per-step renorm + empty-lane adoption; steady
// renorm every 4 steps (floor 2^-93 stays normal; period 8 would risk FTZ).
// Zero transcendentals on the chain; log only at readout.
// log-softmax normalizer: sum_c(p+EPS) == 1 + C*EPS exactly -> constant.

constexpr int   T_    = 512;
constexpr int   C_    = 96;
constexpr int   L_    = 64;
constexpr int   TP_   = 510;          // T - 2
constexpr float EPS_  = 1e-7f;
constexpr float LN2_  = 0.69314718055994530942f;
constexpr float LSE1_ = 1.3849806e-5f;   // log2(1 + C_*EPS_)

typedef float f8 __attribute__((ext_vector_type(8)));
typedef float f2 __attribute__((ext_vector_type(2)));

__device__ __forceinline__ float flog2(float x) {
#if __has_builtin(__builtin_amdgcn_logf)
  return __builtin_amdgcn_logf(x);
#else
  return log2f(x);
#endif
}
__device__ __forceinline__ float fexp2(float x) {
#if __has_builtin(__builtin_amdgcn_exp2f)
  return __builtin_amdgcn_exp2f(x);
#else
  return exp2f(x);
#endif
}
__device__ __forceinline__ float fldexp(float x, int n) {
#if __has_builtin(__builtin_amdgcn_ldexpf)
  return __builtin_amdgcn_ldexpf(x, n);
#else
  return __builtin_ldexpf(x, n);   // lowers to v_ldexp_f32
#endif
}

template<int CTRL, int RM, int BM, bool BC>
__device__ __forceinline__ float dppf(float old_, float src) {
  return __int_as_float(__builtin_amdgcn_update_dpp(
      __float_as_int(old_), __float_as_int(src), CTRL, RM, BM, BC));
}
template<int CTRL, int RM, int BM, bool BC>
__device__ __forceinline__ int dppi(int old_, int src) {
  return __builtin_amdgcn_update_dpp(old_, src, CTRL, RM, BM, BC);
}

// log2(2^x + 2^y) — readout only
__device__ __forceinline__ float lae2(float x, float y) {
  float m = fmaxf(x, y);
  return m + flog2(1.f + fexp2(-fabsf(x - y)));
}

// ---- ring macros: literal element names only (SROA-safe, r5-validated) ----
#define LOADG(PL, PB, T0) {                                         \
  const float* _bl = colL + (size_t)(T0) * C_;                      \
  const float* _bb = colB + (size_t)(T0) * C_;                      \
  PL.s0=_bl[0*C_]; PB.s0=_bb[0*C_]; PL.s1=_bl[1*C_]; PB.s1=_bb[1*C_];\
  PL.s2=_bl[2*C_]; PB.s2=_bb[2*C_]; PL.s3=_bl[3*C_]; PB.s3=_bb[3*C_];\
  PL.s4=_bl[4*C_]; PB.s4=_bb[4*C_]; PL.s5=_bl[5*C_]; PB.s5=_bb[5*C_];\
  PL.s6=_bl[6*C_]; PB.s6=_bb[6*C_]; PL.s7=_bl[7*C_]; PB.s7=_bb[7*C_]; }

#define LD1C(PL, PB, T0, J) {                                       \
  int _t = (T0) + (J); _t = _t < TP_ ? _t : TP_ - 1;                \
  PL.s##J = colL[(size_t)_t * C_]; PB.s##J = colB[(size_t)_t * C_]; }
#define LOADGC(PL, PB, T0) \
  LD1C(PL,PB,T0,0) LD1C(PL,PB,T0,1) LD1C(PL,PB,T0,2) LD1C(PL,PB,T0,3) \
  LD1C(PL,PB,T0,4) LD1C(PL,PB,T0,5) LD1C(PL,PB,T0,6) LD1C(PL,PB,T0,7)

#define A8(PL, PB) { stepF(PL.s0,PB.s0); stepF(PL.s1,PB.s1);        \
  stepF(PL.s2,PB.s2); stepF(PL.s3,PB.s3); stepF(PL.s4,PB.s4);       \
  stepF(PL.s5,PB.s5); stepF(PL.s6,PB.s6); stepF(PL.s7,PB.s7); }

#define B8(PL, PB) { stepS(PL.s0,PB.s0); stepS(PL.s1,PB.s1);        \
  stepS(PL.s2,PB.s2); stepS(PL.s3,PB.s3); renormS();                \
  stepS(PL.s4,PB.s4); stepS(PL.s5,PB.s5); stepS(PL.s6,PB.s6);       \
  stepS(PL.s7,PB.s7); renormS(); }

#define TAIL1(PL, PB, J, OFF) \
  if ((tb + (OFF) + (J)) < tmax) stepF(PL.s##J, PB.s##J);
#define TAIL8(PL, PB, OFF) \
  TAIL1(PL,PB,0,OFF) TAIL1(PL,PB,1,OFF) TAIL1(PL,PB,2,OFF) TAIL1(PL,PB,3,OFF) \
  TAIL1(PL,PB,4,OFF) TAIL1(PL,PB,5,OFF) TAIL1(PL,PB,6,OFF) TAIL1(PL,PB,7,OFF)

__global__ __launch_bounds__(64, 1) void ctc_fwd(
    const int* __restrict__ y_true, const float* __restrict__ y_pred,
    const int* __restrict__ input_len, const int* __restrict__ label_len,
    float* __restrict__ out)
{
  const int b = blockIdx.x;
  const int l = threadIdx.x;   // 0..63

  const float* __restrict__ rp = y_pred + (size_t)b * T_ * C_ + 2 * C_;
  const int  lab     = y_true[b * L_ + l];        // label of odd state 2l+1
  const int  labPrev = __shfl_up(lab, 1);
  const float skipM  = (l >= 1 && lab != labPrev) ? 1.f : 0.f;
  const int  ilen    = input_len[b];
  const int  llen    = label_len[b];               // in [16, 64]
  const int  tmax    = ilen < TP_ ? ilen : TP_;    // 510 for this data

  const float* __restrict__ colL = rp + lab;       // per-lane column
  const float* __restrict__ colB = rp + (C_ - 1);  // uniform (blank) column

  // per-lane scaled-linear state: alpha = m * 2^e ; m = (mE, mO)
  f2    m;
  float mX = 0.f;
  int   e = 0, d = 0;
  m.x = (l == 0) ? (colB[0] + EPS_) : 0.f;
  m.y = (l == 0) ? (colL[0] + EPS_) : 0.f;

  f8 pl0, pl1, pl2, pl3, pb0, pb1, pb2, pb3;
  LOADG(pl0, pb0, 1);  LOADG(pl1, pb1, 9);
  LOADG(pl2, pb2, 17); LOADG(pl3, pb3, 25);

  auto runDP = [&](auto has128) {
    constexpr bool H128 = decltype(has128)::value;

    // fill-phase / tail step: per-step renorm + empty-lane adoption (r5)
    auto stepF = [&](float pl, float pb) {
      float plE = pl + EPS_, pbE = pb + EPS_;
      int   en  = dppi<0x138, 0xf, 0xf, false>(0, e);      // wave_shr1
      float m1  = dppf<0x138, 0xf, 0xf, false>(0.f, m.y);
      int   dd  = en - e;  dd = dd < 120 ? dd : 120;
      float a1  = fldexp(m1, dd);
      float nE  = (m.x + a1) * pbE;
      float nO  = fmaf(a1, skipM, m.y + m.x) * plE;
      float nX = 0.f, mx;
      if constexpr (H128) { nX = (mX + m.y) * pbE; mx = fmaxf(fmaxf(nE, nO), nX); }
      else                { mx = fmaxf(nE, nO); }
      int  kb = __float_as_int(mx) >> 23;
      int  ks = 127 - kb;
      bool z  = (mx == 0.f);
      e  = z ? en : (e + kb - 127);
      m.x = fldexp(nE, ks);
      m.y = fldexp(nO, ks);
      if constexpr (H128) mX = fldexp(nX, ks);
    };

    // steady step: packed-FP32 pair update; e, d frozen since last renormS
    auto stepS = [&](float pl, float pb) {
      f2 p2;  p2.x = pb + EPS_;  p2.y = pl + EPS_;
      float m1 = dppf<0x138, 0xf, 0xf, false>(0.f, m.y);
      float a1 = fldexp(m1, d);
      float t  = fmaf(a1, skipM, m.x);     // mE + a1*skipM
      if constexpr (H128) mX = (mX + m.y) * p2.x;
      f2 ad;  ad.x = a1;  ad.y = t;
      m = (m + ad) * p2;    // v_pk_add_f32 + v_pk_mul_f32:
                            // (mE+a1)*pbE , (mO+mE+a1*skipM)*plE
    };

    auto renormS = [&]() {
      float mx = fmaxf(m.x, m.y);
      if constexpr (H128) mx = fmaxf(mx, mX);
      int kb = __float_as_int(mx) >> 23;   // mx > 0, normal in steady phase
      int ks = 127 - kb;
      e += kb - 127;
      m.x = fldexp(m.x, ks);
      m.y = fldexp(m.y, ks);
      if constexpr (H128) mX = fldexp(mX, ks);
      int en = dppi<0x138, 0xf, 0xf, false>(0, e);
      int dd = en - e;  d = dd < 120 ? dd : 120;
    };

    int tb = 1;
    // Phase A: robust full blocks until all lanes filled (t > 64)
#pragma unroll 1
    for (; tb < 65 && tb + 64 <= tmax; tb += 32) {
      A8(pl0, pb0); LOADG(pl0, pb0, tb + 32);
      A8(pl1, pb1); LOADG(pl1, pb1, tb + 40);
      A8(pl2, pb2); LOADG(pl2, pb2, tb + 48);
      A8(pl3, pb3); LOADG(pl3, pb3, tb + 56);
    }
    // Phase B: steady, renorm every 4 steps
    renormS();
#pragma unroll 1
    for (; tb + 64 <= tmax; tb += 32) {
      B8(pl0, pb0); LOADG(pl0, pb0, tb + 32);
      B8(pl1, pb1); LOADG(pl1, pb1, tb + 40);
      B8(pl2, pb2); LOADG(pl2, pb2, tb + 48);
      B8(pl3, pb3); LOADG(pl3, pb3, tb + 56);
    }
    // Phase C: at most one full block with clamped refills (robust steps)
#pragma unroll 1
    for (; tb + 32 <= tmax; tb += 32) {
      A8(pl0, pb0); LOADGC(pl0, pb0, tb + 32);
      A8(pl1, pb1); LOADGC(pl1, pb1, tb + 40);
      A8(pl2, pb2); LOADGC(pl2, pb2, tb + 48);
      A8(pl3, pb3); LOADGC(pl3, pb3, tb + 56);
    }
    // Phase D: guarded tail (rings hold t = tb .. tb+31)
    TAIL8(pl0, pb0, 0); TAIL8(pl1, pb1, 8);
    TAIL8(pl2, pb2, 16); TAIL8(pl3, pb3, 24);
  };

  if (llen >= 64) runDP(std::integral_constant<bool, true>{});
  else            runDP(std::integral_constant<bool, false>{});

  // readout: log2(alpha) = log2(m) + e   (transcendentals only here)
  float ef  = (float)e;
  float lgE = flog2(m.x) + ef;
  float lgO = flog2(m.y) + ef;
  float aL;
  if (llen >= 64) { float lgX = flog2(mX) + ef; aL = __shfl(lgX, 63); }
  else            { aL = __shfl(lgE, llen); }
  float aP = __shfl(lgO, llen - 1);
  if (l == 0)
    out[b] = -LN2_ * (lae2(aL, aP) - (float)tmax * LSE1_);
}

extern "C" void kernel_launch(void* const* d_in, const int* in_sizes, int n_in,
                              void* d_out, int out_size, void* d_ws, size_t ws_size,
                              hipStream_t stream) {
  const int*   y_true = (const int*)d_in[0];
  const float* y_pred = (const float*)d_in[1];
  const int*   ilen   = (const int*)d_in[2];
  const int*   llen   = (const int*)d_in[3];
  float*       outp   = (float*)d_out;
  const int    B      = out_size;   // 512
  hipLaunchKernelGGL(ctc_fwd, dim3(B), dim3(64), 0, stream,
                     y_true, y_pred, ilen, llen, outp);
}